// Round 6
// baseline (827.953 us; speedup 1.0000x reference)
//
#include <hip/hip_runtime.h>
#include <math.h>

#define HOP 441
#define NMEL 80

typedef float f2 __attribute__((ext_vector_type(2)));

__device__ __forceinline__ f2 mk2(float a, float b) { f2 r; r.x = a; r.y = b; return r; }
// complex mul: 2 packed instrs (pk_mul + pk_fma with neg_lo folded)
__device__ __forceinline__ f2 cmul(f2 a, f2 b) {
    const f2 w = a.yy * b.yx;              // (a.y*b.y, a.y*b.x)
    return a.xx * b + mk2(-w.x, w.y);      // (a.x*b.x - a.y*b.y, a.x*b.y + a.y*b.x)
}
__device__ __forceinline__ f2 shx2(f2 v, int m) {
    f2 r; r.x = __shfl_xor(v.x, m, 64); r.y = __shfl_xor(v.y, m, 64); return r;
}
__device__ __forceinline__ f2 shidx2(f2 v, int src) {
    f2 r; r.x = __shfl(v.x, src, 64); r.y = __shfl(v.y, src, 64); return r;
}
__device__ __forceinline__ int brev6f(int v) {
    return ((v & 1) << 5) | ((v & 2) << 3) | ((v & 4) << 1) |
           ((v & 8) >> 1) | ((v & 16) >> 3) | ((v & 32) >> 5);
}
__device__ __forceinline__ int brevn(int v, int bits) {
    int r = 0;
    for (int i = 0; i < bits; ++i) r |= ((v >> i) & 1) << (bits - 1 - i);
    return r;
}
// w32(m) = exp(-2*pi*i*m/32), m in [0,16) — compile-time constants
__device__ __forceinline__ f2 w32t(int m) {
    constexpr float C[16] = {1.0f, 0.980785280f, 0.923879533f, 0.831469612f,
                             0.707106781f, 0.555570233f, 0.382683432f, 0.195090322f,
                             0.0f, -0.195090322f, -0.382683432f, -0.555570233f,
                             -0.707106781f, -0.831469612f, -0.923879533f, -0.980785280f};
    constexpr float S[16] = {0.0f, 0.195090322f, 0.382683432f, 0.555570233f,
                             0.707106781f, 0.831469612f, 0.923879533f, 0.980785280f,
                             1.0f, 0.980785280f, 0.923879533f, 0.831469612f,
                             0.707106781f, 0.555570233f, 0.382683432f, 0.195090322f};
    return mk2(C[m], -S[m]);
}
__device__ __forceinline__ unsigned short bf16t(float v) {
    return (unsigned short)(__float_as_uint(v) >> 16);
}

// One wave = one frame, natural lane labeling (coalesced loads).
//  1) lane-local R-point DIT FFT (packed f32 complex math)
//  2) per-lane twiddle w_N^(p*r): 4 independent chains stepped by wl^4 (depth R/4)
//  3) cross-lane 64-pt DIF via shfl_xor masks 32..1, twiddle/sign per-lane consts
//  4) rfft unpack, mirror = shfl_xor(63); c-twiddle in 4 chains; bf16 power ->
//     row-swizzled LDS. 8 waves = 8 frames; 1 barrier; shared mel (packed fma).
template<int FLEN, int SZI>
__global__ __launch_bounds__(512, 4)
void spect_kernel(const float* __restrict__ x, const float* __restrict__ win,
                  const float* __restrict__ mel, float* __restrict__ out,
                  int T, int n0) {
    constexpr int N    = FLEN / 2;                  // complex FFT size
    constexpr int R    = N / 64;                    // regs (complex) per lane
    constexpr int LOGR = (R == 32) ? 5 : ((R == 16) ? 4 : 3);
    constexpr int K    = N + 1;                     // rfft bins
    constexpr int KP   = N + 8;
    constexpr int HALF = FLEN / 2;
    constexpr int NT   = 512;
    constexpr int FPB  = 8;                         // frames per block (= waves)
    constexpr float PI = 3.14159265358979f;

    __shared__ uint4 pows4[KP];                     // bf16 power, row-swizzled [k][frame8]
    __shared__ float res[FPB * NMEL];
    unsigned short* pows = (unsigned short*)pows4;

    const int tid = threadIdx.x;
    const int sub = tid >> 6;                       // wave = frame
    const int p   = tid & 63;                       // lane = input index
    const int s   = brev6f(p);                      // output bin block of this lane
    const int b   = blockIdx.y;
    const int t0  = blockIdx.x * FPB;

    for (int i = tid; i < FPB * NMEL; i += NT) res[i] = 0.0f;

    // per-lane stage constants: W' = (p&m)? w_{2m}^{p&(m-1)} : 1 ; sgn = (p&m)? -1:+1
    f2 W32s, W16s, W8s, W4s, W2s, wl, Pp, ub;
    float sg32, sg16, sg8, sg4, sg2, sg1;
    {
        float s_, c_;
        __sincosf(-PI * (float)(p & 31) / 32.0f, &s_, &c_);
        W32s = (p & 32) ? mk2(c_, s_) : mk2(1.0f, 0.0f);
        sg32 = (p & 32) ? -1.0f : 1.0f;
        __sincosf(-PI * (float)(p & 15) / 16.0f, &s_, &c_);
        W16s = (p & 16) ? mk2(c_, s_) : mk2(1.0f, 0.0f);
        sg16 = (p & 16) ? -1.0f : 1.0f;
        __sincosf(-PI * (float)(p & 7) / 8.0f, &s_, &c_);
        W8s  = (p & 8) ? mk2(c_, s_) : mk2(1.0f, 0.0f);
        sg8  = (p & 8) ? -1.0f : 1.0f;
        __sincosf(-PI * (float)(p & 3) / 4.0f, &s_, &c_);
        W4s  = (p & 4) ? mk2(c_, s_) : mk2(1.0f, 0.0f);
        sg4  = (p & 4) ? -1.0f : 1.0f;
        __sincosf(-PI * (float)(p & 1) / 2.0f, &s_, &c_);
        W2s  = (p & 2) ? mk2(c_, s_) : mk2(1.0f, 0.0f);
        sg2  = (p & 2) ? -1.0f : 1.0f;
        sg1  = (p & 1) ? -1.0f : 1.0f;
        __sincosf(-2.0f * PI * (float)p / (float)N, &s_, &c_); wl = mk2(c_, s_);
        __sincosf(PI * (float)s / 64.0f, &s_, &c_);             Pp = mk2(c_, s_);
        __sincosf(PI / (float)N, &s_, &c_);                     ub = mk2(c_, s_);
    }
    const int mpart = brev6f((64 - s) & 63);        // r=0 mirror partner lane

    const float* xb = x + (size_t)b * (size_t)T;
    const int Tp = T + HALF;

    const int t = t0 + sub;
    const bool valid = (t < n0);
    const int start = HOP * t;
    int pad = start + FLEN - Tp; if (pad < 0) pad = 0;
    const int base = start - pad - HALF;

    f2 z[R];
    // coalesced load: reg j holds sample q = brev(j); index i = 64q + p
    #pragma unroll
    for (int j = 0; j < R; ++j) {
        const int q  = brevn(j, LOGR);
        const int i  = 64 * q + p;
        const int j0 = 2 * i;
        const f2 wv = ((const f2*)win)[i];
        const int xi0 = base + j0;
        float v0 = (valid && j0 >= pad     && xi0 >= 0)     ? xb[xi0] * wv.x     : 0.0f;
        float v1 = (valid && j0 + 1 >= pad && xi0 + 1 >= 0) ? xb[xi0 + 1] * wv.y : 0.0f;
        z[j] = mk2(v0, v1);
    }

    // 1) lane-local R-point DIT FFT (output natural order r = reg index)
    #pragma unroll
    for (int h = 1; h < R; h <<= 1) {
        #pragma unroll
        for (int base2 = 0; base2 < R; base2 += 2 * h) {
            #pragma unroll
            for (int i = 0; i < h; ++i) {
                const f2 W  = w32t((16 * i) / h);
                const f2 tt = cmul(W, z[base2 + i + h]);
                const f2 aa = z[base2 + i];
                z[base2 + i]     = aa + tt;
                z[base2 + i + h] = aa - tt;
            }
        }
    }

    // 2) twiddle w_N^(p*r): 4 independent chains stepped by wl^4 (depth ~R/4)
    {
        const f2 w2c = cmul(wl, wl);
        const f2 w3c = cmul(w2c, wl);
        const f2 w4c = cmul(w2c, w2c);
        z[1] = cmul(z[1], wl);
        z[2] = cmul(z[2], w2c);
        z[3] = cmul(z[3], w3c);
        f2 a0 = w4c, a1 = cmul(wl, w4c), a2 = cmul(w2c, w4c), a3 = cmul(w3c, w4c);
        #pragma unroll
        for (int g = 4; g < R; g += 4) {
            z[g]     = cmul(z[g],     a0);
            z[g + 1] = cmul(z[g + 1], a1);
            z[g + 2] = cmul(z[g + 2], a2);
            z[g + 3] = cmul(z[g + 3], a3);
            if (g + 4 < R) {
                a0 = cmul(a0, w4c); a1 = cmul(a1, w4c);
                a2 = cmul(a2, w4c); a3 = cmul(a3, w4c);
            }
        }
    }

    // 3) cross-lane 64-point DIF FFT, masks 32..2 twiddled, mask 1 free
#define XSTAGE(MASK, W, SG) { \
        _Pragma("unroll") \
        for (int j = 0; j < R; ++j) { \
            const f2 xq = shx2(z[j], MASK); \
            const f2 d  = xq + (SG) * z[j]; \
            z[j] = cmul(d, W); \
        } }
    XSTAGE(32, W32s, sg32)
    XSTAGE(16, W16s, sg16)
    XSTAGE(8,  W8s,  sg8)
    XSTAGE(4,  W4s,  sg4)
    XSTAGE(2,  W2s,  sg2)
    #pragma unroll
    for (int j = 0; j < R; ++j) {                   // final stage: twiddle-free
        const f2 xq = shx2(z[j], 1);
        z[j] = xq + sg1 * z[j];
    }
#undef XSTAGE

    // 4) rfft unpack: lane p reg r holds Z[R*s + r]; mirror Z[N-k] at lane p^63 reg R-r
#define EMIT(RR, ZK, ZN, CW, SW) { \
        const f2 sv = (ZK) + (ZN); \
        const f2 dv = (ZK) - (ZN); \
        const float Er = 0.5f * sv.x, Ei = 0.5f * dv.y; \
        const float Or = 0.5f * sv.y, Oi = -0.5f * dv.x; \
        const float Xr = Er + (CW) * Or + (SW) * Oi; \
        const float Xi = Ei + (CW) * Oi - (SW) * Or; \
        const float pw = Xr * Xr + Xi * Xi; \
        const int row = R * s + ((RR) ^ (s & 7)); \
        pows[row * 8 + sub] = bf16t(pw); }

    {
        const f2 ub2 = cmul(ub, ub);
        const f2 ub4 = cmul(ub2, ub2);
        f2 c0 = Pp, c1 = cmul(Pp, ub), c2 = cmul(Pp, ub2), c3 = cmul(c1, ub2);
        {   // r = 0: mirror at lane brev6((64-s)&63), reg 0
            const f2 Zn = shidx2(z[0], mpart);
            EMIT(0, z[0], Zn, c0.x, c0.y)
        }
        { const f2 Zn = shx2(z[R - 1], 63); EMIT(1, z[1], Zn, c1.x, c1.y) }
        { const f2 Zn = shx2(z[R - 2], 63); EMIT(2, z[2], Zn, c2.x, c2.y) }
        { const f2 Zn = shx2(z[R - 3], 63); EMIT(3, z[3], Zn, c3.x, c3.y) }
        #pragma unroll
        for (int g = 4; g < R; g += 4) {
            c0 = cmul(c0, ub4); c1 = cmul(c1, ub4);
            c2 = cmul(c2, ub4); c3 = cmul(c3, ub4);
            { const f2 Zn = shx2(z[R - g],     63); EMIT(g,     z[g],     Zn, c0.x, c0.y) }
            { const f2 Zn = shx2(z[R - g - 1], 63); EMIT(g + 1, z[g + 1], Zn, c1.x, c1.y) }
            { const f2 Zn = shx2(z[R - g - 2], 63); EMIT(g + 2, z[g + 2], Zn, c2.x, c2.y) }
            { const f2 Zn = shx2(z[R - g - 3], 63); EMIT(g + 3, z[g + 3], Zn, c3.x, c3.y) }
        }
        if (p == 0) {                               // bin k = N (s=0 lane holds Z[0])
            const float xr = z[0].x - z[0].y;
            pows[N * 8 + sub] = bf16t(xr * xr);
        }
    }
#undef EMIT

    __syncthreads();   // pows + res ready for mel phase

    // ---- mel: out[f][m] = sum_k pow[k][f] * mel[k][m]; rows XOR-swizzled ----
    constexpr int NCH = 25;
    constexpr int CH  = (K + NCH - 1) / NCH;
    if (tid < NCH * 20) {
        const int g  = tid % 20;                    // mel bins 4g..4g+3
        const int cc = tid / 20;                    // k-chunk
        const int k0 = cc * CH;
        const int k1 = (k0 + CH < K) ? (k0 + CH) : K;
        f2 acc[FPB][2];
        #pragma unroll
        for (int f3 = 0; f3 < FPB; ++f3) { acc[f3][0] = mk2(0.f, 0.f); acc[f3][1] = mk2(0.f, 0.f); }
        for (int k = k0; k < k1; ++k) {
            const int kmel = (k & ~(R - 1)) | ((k & (R - 1)) ^ ((k >> LOGR) & 7));
            const float4 mr = *(const float4*)(mel + (size_t)kmel * NMEL + 4 * g);
            const f2 m01 = mk2(mr.x, mr.y);
            const f2 m23 = mk2(mr.z, mr.w);
            const uint4 pv = pows4[k];
#define ACC2(W32, BASE) { \
            const float p0 = __uint_as_float((W32) << 16); \
            const float p1 = __uint_as_float((W32) & 0xFFFF0000u); \
            acc[BASE][0] += p0 * m01;       acc[BASE][1] += p0 * m23; \
            acc[(BASE)+1][0] += p1 * m01;   acc[(BASE)+1][1] += p1 * m23; }
            ACC2(pv.x, 0) ACC2(pv.y, 2) ACC2(pv.z, 4) ACC2(pv.w, 6)
#undef ACC2
        }
        #pragma unroll
        for (int f3 = 0; f3 < FPB; ++f3) {
            atomicAdd(&res[f3 * NMEL + 4 * g + 0], acc[f3][0].x);
            atomicAdd(&res[f3 * NMEL + 4 * g + 1], acc[f3][0].y);
            atomicAdd(&res[f3 * NMEL + 4 * g + 2], acc[f3][1].x);
            atomicAdd(&res[f3 * NMEL + 4 * g + 3], acc[f3][1].y);
        }
    }
    __syncthreads();

    const size_t outbase = (size_t)b * (size_t)n0 * NMEL * 3;
    for (int i = tid; i < FPB * NMEL; i += NT) {
        const int f3 = i / NMEL;
        const int m  = i % NMEL;
        const int tt = t0 + f3;
        if (tt < n0) {
            out[outbase + ((size_t)tt * NMEL + m) * 3 + SZI] = logf(res[i] + 1e-16f);
        }
    }
}

extern "C" void kernel_launch(void* const* d_in, const int* in_sizes, int n_in,
                              void* d_out, int out_size, void* d_ws, size_t ws_size,
                              hipStream_t stream) {
    const float* x  = (const float*)d_in[0];
    const float* w1 = (const float*)d_in[1];
    const float* m1 = (const float*)d_in[2];
    const float* w2 = (const float*)d_in[3];
    const float* m2 = (const float*)d_in[4];
    const float* w4 = (const float*)d_in[5];
    const float* m4 = (const float*)d_in[6];
    float* out = (float*)d_out;

    const int B  = 8;
    const int T  = in_sizes[0] / B;
    const int n0 = (T + 512 + 440) / 441;   // ceil((T + 1024/2) / 441)
    const int gx = (n0 + 7) / 8;

    spect_kernel<1024, 0><<<dim3(gx, B), 512, 0, stream>>>(x, w1, m1, out, T, n0);
    spect_kernel<2048, 1><<<dim3(gx, B), 512, 0, stream>>>(x, w2, m2, out, T, n0);
    spect_kernel<4096, 2><<<dim3(gx, B), 512, 0, stream>>>(x, w4, m4, out, T, n0);
}

// Round 7
// 774.033 us; speedup vs baseline: 1.0697x; 1.0697x over previous
//
#include <hip/hip_runtime.h>
#include <math.h>

#define HOP 441
#define NMEL 80

__device__ __forceinline__ float2 cmulf(float2 a, float2 b) {
    return make_float2(a.x * b.x - a.y * b.y, a.x * b.y + a.y * b.x);
}
__device__ __forceinline__ float2 cadd(float2 a, float2 b) {
    return make_float2(a.x + b.x, a.y + b.y);
}
__device__ __forceinline__ float2 csub(float2 a, float2 b) {
    return make_float2(a.x - b.x, a.y - b.y);
}
__device__ __forceinline__ float2 shx2(float2 v, int m) {
    return make_float2(__shfl_xor(v.x, m, 64), __shfl_xor(v.y, m, 64));
}
__device__ __forceinline__ float2 shidx2(float2 v, int src) {
    return make_float2(__shfl(v.x, src, 64), __shfl(v.y, src, 64));
}
__device__ __forceinline__ int brev6f(int v) {
    return ((v & 1) << 5) | ((v & 2) << 3) | ((v & 4) << 1) |
           ((v & 8) >> 1) | ((v & 16) >> 3) | ((v & 32) >> 5);
}
__device__ __forceinline__ int brevn(int v, int bits) {
    int r = 0;
    for (int i = 0; i < bits; ++i) r |= ((v >> i) & 1) << (bits - 1 - i);
    return r;
}
// w32(m) = exp(-2*pi*i*m/32), m in [0,16) — compile-time constants
__device__ __forceinline__ float2 w32t(int m) {
    constexpr float C[16] = {1.0f, 0.980785280f, 0.923879533f, 0.831469612f,
                             0.707106781f, 0.555570233f, 0.382683432f, 0.195090322f,
                             0.0f, -0.195090322f, -0.382683432f, -0.555570233f,
                             -0.707106781f, -0.831469612f, -0.923879533f, -0.980785280f};
    constexpr float S[16] = {0.0f, 0.195090322f, 0.382683432f, 0.555570233f,
                             0.707106781f, 0.831469612f, 0.923879533f, 0.980785280f,
                             1.0f, 0.980785280f, 0.923879533f, 0.831469612f,
                             0.707106781f, 0.555570233f, 0.382683432f, 0.195090322f};
    return make_float2(C[m], -S[m]);
}
__device__ __forceinline__ unsigned short bf16t(float v) {
    return (unsigned short)(__float_as_uint(v) >> 16);
}

// One wave = one frame, natural lane labeling (coalesced loads).
//  1) lane-local R-point DIT FFT  2) per-lane twiddle w_N^(p*r), 4 chains
//  3) cross-lane 64-pt DIF via shfl_xor masks 32..1 (per-lane folded consts)
//  4) PAIR rfft unpack: X[k]=E+W*O, X[N-k]=(E-W*O)* -> both powers from one
//     (Zk,Zn) pair; shuffles halved. bf16 power -> involution-swizzled LDS rows.
// 8 waves = 8 frames; 1 barrier; shared mel matmul; log; strided store.
template<int FLEN, int SZI>
__global__ __launch_bounds__(512, 4)
void spect_kernel(const float* __restrict__ x, const float* __restrict__ win,
                  const float* __restrict__ mel, float* __restrict__ out,
                  int T, int n0) {
    constexpr int N    = FLEN / 2;                  // complex FFT size
    constexpr int R    = N / 64;                    // regs (complex) per lane
    constexpr int LOGR = (R == 32) ? 5 : ((R == 16) ? 4 : 3);
    constexpr int R2_  = R / 2;
    constexpr int K    = N + 1;                     // rfft bins
    constexpr int KP   = N + 8;
    constexpr int HALF = FLEN / 2;
    constexpr int NT   = 512;
    constexpr int FPB  = 8;                         // frames per block (= waves)
    constexpr float PI = 3.14159265358979f;

    __shared__ uint4 pows4[KP];                     // bf16 power, swizzled rows [k][frame8]
    __shared__ float res[FPB * NMEL];
    unsigned short* pows = (unsigned short*)pows4;

    const int tid = threadIdx.x;
    const int sub = tid >> 6;                       // wave = frame
    const int p   = tid & 63;                       // lane = input index
    const int s   = brev6f(p);                      // output bin block of this lane
    const int b   = blockIdx.y;
    const int t0  = blockIdx.x * FPB;

    for (int i = tid; i < FPB * NMEL; i += NT) res[i] = 0.0f;

    // per-lane stage constants: W' = (p&m)? w_{2m}^{p&(m-1)} : 1 ; sgn = (p&m)? -1:+1
    float2 W32s, W16s, W8s, W4s, W2s, wl, Pp, ub;
    float sg32, sg16, sg8, sg4, sg2, sg1;
    {
        float s_, c_;
        __sincosf(-PI * (float)(p & 31) / 32.0f, &s_, &c_);
        W32s = (p & 32) ? make_float2(c_, s_) : make_float2(1.0f, 0.0f);
        sg32 = (p & 32) ? -1.0f : 1.0f;
        __sincosf(-PI * (float)(p & 15) / 16.0f, &s_, &c_);
        W16s = (p & 16) ? make_float2(c_, s_) : make_float2(1.0f, 0.0f);
        sg16 = (p & 16) ? -1.0f : 1.0f;
        __sincosf(-PI * (float)(p & 7) / 8.0f, &s_, &c_);
        W8s  = (p & 8) ? make_float2(c_, s_) : make_float2(1.0f, 0.0f);
        sg8  = (p & 8) ? -1.0f : 1.0f;
        __sincosf(-PI * (float)(p & 3) / 4.0f, &s_, &c_);
        W4s  = (p & 4) ? make_float2(c_, s_) : make_float2(1.0f, 0.0f);
        sg4  = (p & 4) ? -1.0f : 1.0f;
        __sincosf(-PI * (float)(p & 1) / 2.0f, &s_, &c_);
        W2s  = (p & 2) ? make_float2(c_, s_) : make_float2(1.0f, 0.0f);
        sg2  = (p & 2) ? -1.0f : 1.0f;
        sg1  = (p & 1) ? -1.0f : 1.0f;
        __sincosf(-2.0f * PI * (float)p / (float)N, &s_, &c_); wl = make_float2(c_, s_);
        __sincosf(PI * (float)s / 64.0f, &s_, &c_);             Pp = make_float2(c_, s_);
        __sincosf(PI / (float)N, &s_, &c_);                     ub = make_float2(c_, s_);
    }
    const int mpart = brev6f((64 - s) & 63);        // r=0 mirror partner lane

    const float* xb = x + (size_t)b * (size_t)T;
    const int Tp = T + HALF;

    const int t = t0 + sub;
    const bool valid = (t < n0);
    const int start = HOP * t;
    int pad = start + FLEN - Tp; if (pad < 0) pad = 0;
    const int base = start - pad - HALF;

    float2 z[R];
    // coalesced load: reg j holds sample q = brev(j); index i = 64q + p
    if (pad == 0 && base >= 0 && valid) {
        // fast path (interior frames, ~99%): no masks, fixed base + imm offsets
        const float*  xp = xb + base + 2 * p;
        const float2* wp = ((const float2*)win) + p;
        #pragma unroll
        for (int j = 0; j < R; ++j) {
            const int q = brevn(j, LOGR);
            const float2 wv = wp[64 * q];
            z[j] = make_float2(xp[128 * q] * wv.x, xp[128 * q + 1] * wv.y);
        }
    } else {
        #pragma unroll
        for (int j = 0; j < R; ++j) {
            const int q  = brevn(j, LOGR);
            const int i  = 64 * q + p;
            const int j0 = 2 * i;
            const float2 wv = ((const float2*)win)[i];
            const int xi0 = base + j0;
            float v0 = (valid && j0 >= pad     && xi0 >= 0)     ? xb[xi0] * wv.x     : 0.0f;
            float v1 = (valid && j0 + 1 >= pad && xi0 + 1 >= 0) ? xb[xi0 + 1] * wv.y : 0.0f;
            z[j] = make_float2(v0, v1);
        }
    }

    // 1) lane-local R-point DIT FFT (output natural order r = reg index)
    #pragma unroll
    for (int h = 1; h < R; h <<= 1) {
        #pragma unroll
        for (int base2 = 0; base2 < R; base2 += 2 * h) {
            #pragma unroll
            for (int i = 0; i < h; ++i) {
                const float2 W  = w32t((16 * i) / h);
                const float2 tt = cmulf(W, z[base2 + i + h]);
                const float2 aa = z[base2 + i];
                z[base2 + i]     = cadd(aa, tt);
                z[base2 + i + h] = csub(aa, tt);
            }
        }
    }

    // 2) twiddle w_N^(p*r): 4 independent chains stepped by wl^4
    {
        const float2 w2c = cmulf(wl, wl);
        const float2 w3c = cmulf(w2c, wl);
        const float2 w4c = cmulf(w2c, w2c);
        z[1] = cmulf(z[1], wl);
        z[2] = cmulf(z[2], w2c);
        z[3] = cmulf(z[3], w3c);
        float2 a0 = w4c, a1 = cmulf(wl, w4c), a2 = cmulf(w2c, w4c), a3 = cmulf(w3c, w4c);
        #pragma unroll
        for (int g = 4; g < R; g += 4) {
            z[g]     = cmulf(z[g],     a0);
            z[g + 1] = cmulf(z[g + 1], a1);
            z[g + 2] = cmulf(z[g + 2], a2);
            z[g + 3] = cmulf(z[g + 3], a3);
            if (g + 4 < R) {
                a0 = cmulf(a0, w4c); a1 = cmulf(a1, w4c);
                a2 = cmulf(a2, w4c); a3 = cmulf(a3, w4c);
            }
        }
    }

    // 3) cross-lane 64-point DIF FFT, masks 32..2 twiddled, mask 1 free
#define XSTAGE(MASK, W, SG) { \
        _Pragma("unroll") \
        for (int j = 0; j < R; ++j) { \
            const float2 xq = shx2(z[j], MASK); \
            const float2 d  = make_float2(fmaf(SG, z[j].x, xq.x), \
                                          fmaf(SG, z[j].y, xq.y)); \
            z[j] = cmulf(d, W); \
        } }
    XSTAGE(32, W32s, sg32)
    XSTAGE(16, W16s, sg16)
    XSTAGE(8,  W8s,  sg8)
    XSTAGE(4,  W4s,  sg4)
    XSTAGE(2,  W2s,  sg2)
    #pragma unroll
    for (int j = 0; j < R; ++j) {                   // final stage: twiddle-free
        const float2 xq = shx2(z[j], 1);
        z[j] = make_float2(fmaf(sg1, z[j].x, xq.x), fmaf(sg1, z[j].y, xq.y));
    }
#undef XSTAGE

    // 4) PAIR rfft unpack: bins k = R*s+r (r<=R/2) AND N-k from one (Zk,Zn):
    //    X[k] = E + T, X[N-k] = (E - T)*  with T = W*O, W = (cw, -sw).
    //    Rows use the self-inverse swizzle (same formula as mel's kmel).
#define PAIRE(RR, ZK, ZN, CW, SW) { \
        const float Er = 0.5f * ((ZK).x + (ZN).x), Ei = 0.5f * ((ZK).y - (ZN).y); \
        const float Or = 0.5f * ((ZK).y + (ZN).y), Oi = -0.5f * ((ZK).x - (ZN).x); \
        const float Tr = (CW) * Or + (SW) * Oi; \
        const float Ti = (CW) * Oi - (SW) * Or; \
        const float Xr0 = Er + Tr, Xi0 = Ei + Ti; \
        const float Xr1 = Er - Tr, Xi1 = Ei - Ti; \
        const float pw0 = Xr0 * Xr0 + Xi0 * Xi0; \
        const float pw1 = Xr1 * Xr1 + Xi1 * Xi1; \
        const int k0b  = R * s + (RR); \
        const int km   = N - k0b; \
        const int row0 = (k0b & ~(R - 1)) | ((k0b & (R - 1)) ^ (s & 7)); \
        const int row1 = (km  & ~(R - 1)) | ((km  & (R - 1)) ^ ((km >> LOGR) & 7)); \
        pows[row0 * 8 + sub] = bf16t(pw0); \
        pows[row1 * 8 + sub] = bf16t(pw1); }

    {
        const float2 ub2 = cmulf(ub, ub);
        const float2 ub4 = cmulf(ub2, ub2);
        float2 c0 = Pp, c1 = cmulf(Pp, ub), c2 = cmulf(Pp, ub2), c3 = cmulf(c1, ub2);
        {   // r = 0: mirror at lane brev6((64-s)&63); covers bin N at s=0
            const float2 Zn = shidx2(z[0], mpart);
            PAIRE(0, z[0], Zn, c0.x, c0.y)
        }
        { const float2 Zn = shx2(z[R - 1], 63); PAIRE(1, z[1], Zn, c1.x, c1.y) }
        { const float2 Zn = shx2(z[R - 2], 63); PAIRE(2, z[2], Zn, c2.x, c2.y) }
        { const float2 Zn = shx2(z[R - 3], 63); PAIRE(3, z[3], Zn, c3.x, c3.y) }
        #pragma unroll
        for (int g = 4; g <= R2_; g += 4) {
            c0 = cmulf(c0, ub4); c1 = cmulf(c1, ub4);
            c2 = cmulf(c2, ub4); c3 = cmulf(c3, ub4);
            { const float2 Zn = shx2(z[R - g], 63); PAIRE(g, z[g], Zn, c0.x, c0.y) }
            if (g + 1 <= R2_) { const float2 Zn = shx2(z[R - g - 1], 63); PAIRE(g + 1, z[g + 1], Zn, c1.x, c1.y) }
            if (g + 2 <= R2_) { const float2 Zn = shx2(z[R - g - 2], 63); PAIRE(g + 2, z[g + 2], Zn, c2.x, c2.y) }
            if (g + 3 <= R2_) { const float2 Zn = shx2(z[R - g - 3], 63); PAIRE(g + 3, z[g + 3], Zn, c3.x, c3.y) }
        }
    }
#undef PAIRE

    __syncthreads();   // pows + res ready for mel phase

    // ---- mel: out[f][m] = sum_k pow[k][f] * mel[k][m]; rows swizzled (involution) ----
    constexpr int NCH = 25;
    constexpr int CH  = (K + NCH - 1) / NCH;
    if (tid < NCH * 20) {
        const int g  = tid % 20;                    // mel bins 4g..4g+3
        const int cc = tid / 20;                    // k-chunk
        const int k0 = cc * CH;
        const int k1 = (k0 + CH < K) ? (k0 + CH) : K;
        float acc[FPB][4];
        #pragma unroll
        for (int f2 = 0; f2 < FPB; ++f2) {
            acc[f2][0] = 0.f; acc[f2][1] = 0.f; acc[f2][2] = 0.f; acc[f2][3] = 0.f;
        }
        #pragma unroll 4
        for (int k = k0; k < k1; ++k) {
            const int kmel = (k & ~(R - 1)) | ((k & (R - 1)) ^ ((k >> LOGR) & 7));
            const float4 mr = *(const float4*)(mel + (size_t)kmel * NMEL + 4 * g);
            const uint4 pv = pows4[k];
#define ACC2(W32, BASE) { \
            const float p0 = __uint_as_float((W32) << 16); \
            const float p1 = __uint_as_float((W32) & 0xFFFF0000u); \
            acc[BASE][0] += p0 * mr.x; acc[BASE][1] += p0 * mr.y; \
            acc[BASE][2] += p0 * mr.z; acc[BASE][3] += p0 * mr.w; \
            acc[(BASE)+1][0] += p1 * mr.x; acc[(BASE)+1][1] += p1 * mr.y; \
            acc[(BASE)+1][2] += p1 * mr.z; acc[(BASE)+1][3] += p1 * mr.w; }
            ACC2(pv.x, 0) ACC2(pv.y, 2) ACC2(pv.z, 4) ACC2(pv.w, 6)
#undef ACC2
        }
        #pragma unroll
        for (int f2 = 0; f2 < FPB; ++f2) {
            #pragma unroll
            for (int mi = 0; mi < 4; ++mi) {
                atomicAdd(&res[f2 * NMEL + 4 * g + mi], acc[f2][mi]);
            }
        }
    }
    __syncthreads();

    const size_t outbase = (size_t)b * (size_t)n0 * NMEL * 3;
    for (int i = tid; i < FPB * NMEL; i += NT) {
        const int f2 = i / NMEL;
        const int m  = i % NMEL;
        const int tt = t0 + f2;
        if (tt < n0) {
            out[outbase + ((size_t)tt * NMEL + m) * 3 + SZI] = logf(res[i] + 1e-16f);
        }
    }
}

extern "C" void kernel_launch(void* const* d_in, const int* in_sizes, int n_in,
                              void* d_out, int out_size, void* d_ws, size_t ws_size,
                              hipStream_t stream) {
    const float* x  = (const float*)d_in[0];
    const float* w1 = (const float*)d_in[1];
    const float* m1 = (const float*)d_in[2];
    const float* w2 = (const float*)d_in[3];
    const float* m2 = (const float*)d_in[4];
    const float* w4 = (const float*)d_in[5];
    const float* m4 = (const float*)d_in[6];
    float* out = (float*)d_out;

    const int B  = 8;
    const int T  = in_sizes[0] / B;
    const int n0 = (T + 512 + 440) / 441;   // ceil((T + 1024/2) / 441)
    const int gx = (n0 + 7) / 8;

    spect_kernel<1024, 0><<<dim3(gx, B), 512, 0, stream>>>(x, w1, m1, out, T, n0);
    spect_kernel<2048, 1><<<dim3(gx, B), 512, 0, stream>>>(x, w2, m2, out, T, n0);
    spect_kernel<4096, 2><<<dim3(gx, B), 512, 0, stream>>>(x, w4, m4, out, T, n0);
}

// Round 8
// 252.661 us; speedup vs baseline: 3.2769x; 3.0635x over previous
//
#include <hip/hip_runtime.h>
#include <math.h>

#define HOP 441
#define NMEL 80

typedef __attribute__((ext_vector_type(8))) short bf16x8;
typedef __attribute__((ext_vector_type(4))) float f32x4;

__device__ __forceinline__ float2 cmulf(float2 a, float2 b) {
    return make_float2(a.x * b.x - a.y * b.y, a.x * b.y + a.y * b.x);
}
__device__ __forceinline__ float2 cadd(float2 a, float2 b) {
    return make_float2(a.x + b.x, a.y + b.y);
}
__device__ __forceinline__ float2 csub(float2 a, float2 b) {
    return make_float2(a.x - b.x, a.y - b.y);
}
__device__ __forceinline__ float2 shx2(float2 v, int m) {
    return make_float2(__shfl_xor(v.x, m, 64), __shfl_xor(v.y, m, 64));
}
__device__ __forceinline__ float2 shidx2(float2 v, int src) {
    return make_float2(__shfl(v.x, src, 64), __shfl(v.y, src, 64));
}
__device__ __forceinline__ int brev6f(int v) {
    return ((v & 1) << 5) | ((v & 2) << 3) | ((v & 4) << 1) |
           ((v & 8) >> 1) | ((v & 16) >> 3) | ((v & 32) >> 5);
}
__device__ __forceinline__ int brevn(int v, int bits) {
    int r = 0;
    for (int i = 0; i < bits; ++i) r |= ((v >> i) & 1) << (bits - 1 - i);
    return r;
}
__device__ __forceinline__ float2 w32t(int m) {
    constexpr float C[16] = {1.0f, 0.980785280f, 0.923879533f, 0.831469612f,
                             0.707106781f, 0.555570233f, 0.382683432f, 0.195090322f,
                             0.0f, -0.195090322f, -0.382683432f, -0.555570233f,
                             -0.707106781f, -0.831469612f, -0.923879533f, -0.980785280f};
    constexpr float S[16] = {0.0f, 0.195090322f, 0.382683432f, 0.555570233f,
                             0.707106781f, 0.831469612f, 0.923879533f, 0.980785280f,
                             1.0f, 0.980785280f, 0.923879533f, 0.831469612f,
                             0.707106781f, 0.555570233f, 0.382683432f, 0.195090322f};
    return make_float2(C[m], -S[m]);
}
__device__ __forceinline__ unsigned short bf16t(float v) {
    return (unsigned short)(__float_as_uint(v) >> 16);
}

// ================== NEW PATH: FFT kernel (barrier-free) ==================
// One wave = one frame (R7-verified math). bf16 power bins -> per-wave flat
// LDS with involution swizzle swz(k)=k^((k>>LOGR)&(R-1)) (conflict-free
// scatter), then coalesced transpose-out: raw b128 reads -> dwordx4 stores of
// A rows [frame][KPAD]. The k-permutation is NOT undone; the GEMM's melT is
// stored with the same involution (contraction is permutation-invariant).
template<int FLEN, int KPAD>
__global__ __launch_bounds__(256, 4)
void fft_kernel(const float* __restrict__ x, const float* __restrict__ win,
                unsigned short* __restrict__ pows_g, int T, int n0) {
    constexpr int N    = FLEN / 2;
    constexpr int R    = N / 64;
    constexpr int LOGR = (R == 32) ? 5 : ((R == 16) ? 4 : 3);
    constexpr int R2_  = R / 2;
    constexpr int HALF = FLEN / 2;
    constexpr int NOCT = KPAD / 8;
    constexpr float PI = 3.14159265358979f;

    __shared__ uint4 powsU[4 * KPAD / 8];           // 4 waves x KPAD bf16
    unsigned short* ldsw = (unsigned short*)powsU + (threadIdx.x >> 6) * KPAD;

    const int tid = threadIdx.x;
    const int sub = tid >> 6;                       // wave = frame
    const int p   = tid & 63;
    const int s   = brev6f(p);
    const int b   = blockIdx.y;
    const int t0  = blockIdx.x * 4;

    // zero the padded tail rows (N+1 .. KPAD-1); swz is identity/bijective there
    if (p < KPAD - (N + 1)) ldsw[N + 1 + p] = 0;

    float2 W32s, W16s, W8s, W4s, W2s, wl, Pp, ub;
    float sg32, sg16, sg8, sg4, sg2, sg1;
    {
        float s_, c_;
        __sincosf(-PI * (float)(p & 31) / 32.0f, &s_, &c_);
        W32s = (p & 32) ? make_float2(c_, s_) : make_float2(1.0f, 0.0f);
        sg32 = (p & 32) ? -1.0f : 1.0f;
        __sincosf(-PI * (float)(p & 15) / 16.0f, &s_, &c_);
        W16s = (p & 16) ? make_float2(c_, s_) : make_float2(1.0f, 0.0f);
        sg16 = (p & 16) ? -1.0f : 1.0f;
        __sincosf(-PI * (float)(p & 7) / 8.0f, &s_, &c_);
        W8s  = (p & 8) ? make_float2(c_, s_) : make_float2(1.0f, 0.0f);
        sg8  = (p & 8) ? -1.0f : 1.0f;
        __sincosf(-PI * (float)(p & 3) / 4.0f, &s_, &c_);
        W4s  = (p & 4) ? make_float2(c_, s_) : make_float2(1.0f, 0.0f);
        sg4  = (p & 4) ? -1.0f : 1.0f;
        __sincosf(-PI * (float)(p & 1) / 2.0f, &s_, &c_);
        W2s  = (p & 2) ? make_float2(c_, s_) : make_float2(1.0f, 0.0f);
        sg2  = (p & 2) ? -1.0f : 1.0f;
        sg1  = (p & 1) ? -1.0f : 1.0f;
        __sincosf(-2.0f * PI * (float)p / (float)N, &s_, &c_); wl = make_float2(c_, s_);
        __sincosf(PI * (float)s / 64.0f, &s_, &c_);             Pp = make_float2(c_, s_);
        __sincosf(PI / (float)N, &s_, &c_);                     ub = make_float2(c_, s_);
    }
    const int mpart = brev6f((64 - s) & 63);

    const float* xb = x + (size_t)b * (size_t)T;
    const int Tp = T + HALF;

    const int t = t0 + sub;
    const bool valid = (t < n0);
    const int start = HOP * t;
    int pad = start + FLEN - Tp; if (pad < 0) pad = 0;
    const int base = start - pad - HALF;

    float2 z[R];
    if (pad == 0 && base >= 0 && valid) {
        const float*  xp = xb + base + 2 * p;
        const float2* wp = ((const float2*)win) + p;
        #pragma unroll
        for (int j = 0; j < R; ++j) {
            const int q = brevn(j, LOGR);
            const float2 wv = wp[64 * q];
            z[j] = make_float2(xp[128 * q] * wv.x, xp[128 * q + 1] * wv.y);
        }
    } else {
        #pragma unroll
        for (int j = 0; j < R; ++j) {
            const int q  = brevn(j, LOGR);
            const int i  = 64 * q + p;
            const int j0 = 2 * i;
            const float2 wv = ((const float2*)win)[i];
            const int xi0 = base + j0;
            float v0 = (valid && j0 >= pad     && xi0 >= 0)     ? xb[xi0] * wv.x     : 0.0f;
            float v1 = (valid && j0 + 1 >= pad && xi0 + 1 >= 0) ? xb[xi0 + 1] * wv.y : 0.0f;
            z[j] = make_float2(v0, v1);
        }
    }

    // lane-local R-point DIT FFT
    #pragma unroll
    for (int h = 1; h < R; h <<= 1) {
        #pragma unroll
        for (int base2 = 0; base2 < R; base2 += 2 * h) {
            #pragma unroll
            for (int i = 0; i < h; ++i) {
                const float2 W  = w32t((16 * i) / h);
                const float2 tt = cmulf(W, z[base2 + i + h]);
                const float2 aa = z[base2 + i];
                z[base2 + i]     = cadd(aa, tt);
                z[base2 + i + h] = csub(aa, tt);
            }
        }
    }

    // per-lane twiddle w_N^(p*r), 4 independent chains
    {
        const float2 w2c = cmulf(wl, wl);
        const float2 w3c = cmulf(w2c, wl);
        const float2 w4c = cmulf(w2c, w2c);
        z[1] = cmulf(z[1], wl);
        z[2] = cmulf(z[2], w2c);
        z[3] = cmulf(z[3], w3c);
        float2 a0 = w4c, a1 = cmulf(wl, w4c), a2 = cmulf(w2c, w4c), a3 = cmulf(w3c, w4c);
        #pragma unroll
        for (int g = 4; g < R; g += 4) {
            z[g]     = cmulf(z[g],     a0);
            z[g + 1] = cmulf(z[g + 1], a1);
            z[g + 2] = cmulf(z[g + 2], a2);
            z[g + 3] = cmulf(z[g + 3], a3);
            if (g + 4 < R) {
                a0 = cmulf(a0, w4c); a1 = cmulf(a1, w4c);
                a2 = cmulf(a2, w4c); a3 = cmulf(a3, w4c);
            }
        }
    }

    // cross-lane 64-point DIF FFT
#define XSTAGE(MASK, W, SG) { \
        _Pragma("unroll") \
        for (int j = 0; j < R; ++j) { \
            const float2 xq = shx2(z[j], MASK); \
            const float2 d  = make_float2(fmaf(SG, z[j].x, xq.x), \
                                          fmaf(SG, z[j].y, xq.y)); \
            z[j] = cmulf(d, W); \
        } }
    XSTAGE(32, W32s, sg32)
    XSTAGE(16, W16s, sg16)
    XSTAGE(8,  W8s,  sg8)
    XSTAGE(4,  W4s,  sg4)
    XSTAGE(2,  W2s,  sg2)
    #pragma unroll
    for (int j = 0; j < R; ++j) {
        const float2 xq = shx2(z[j], 1);
        z[j] = make_float2(fmaf(sg1, z[j].x, xq.x), fmaf(sg1, z[j].y, xq.y));
    }
#undef XSTAGE

    // PAIR rfft unpack -> swizzled LDS rows
#define SWZK(KK) (((KK) & ~(R - 1)) | (((KK) & (R - 1)) ^ (((KK) >> LOGR) & (R - 1))))
#define PAIRE(RR, ZK, ZN, CW, SW) { \
        const float Er = 0.5f * ((ZK).x + (ZN).x), Ei = 0.5f * ((ZK).y - (ZN).y); \
        const float Or = 0.5f * ((ZK).y + (ZN).y), Oi = -0.5f * ((ZK).x - (ZN).x); \
        const float Tr = (CW) * Or + (SW) * Oi; \
        const float Ti = (CW) * Oi - (SW) * Or; \
        const float Xr0 = Er + Tr, Xi0 = Ei + Ti; \
        const float Xr1 = Er - Tr, Xi1 = Ei - Ti; \
        const float pw0 = Xr0 * Xr0 + Xi0 * Xi0; \
        const float pw1 = Xr1 * Xr1 + Xi1 * Xi1; \
        const int k0b = R * s + (RR); \
        const int km  = N - k0b; \
        ldsw[SWZK(k0b)] = bf16t(pw0); \
        ldsw[SWZK(km)]  = bf16t(pw1); }

    {
        const float2 ub2 = cmulf(ub, ub);
        const float2 ub4 = cmulf(ub2, ub2);
        float2 c0 = Pp, c1 = cmulf(Pp, ub), c2 = cmulf(Pp, ub2), c3 = cmulf(c1, ub2);
        {
            const float2 Zn = shidx2(z[0], mpart);
            PAIRE(0, z[0], Zn, c0.x, c0.y)
        }
        { const float2 Zn = shx2(z[R - 1], 63); PAIRE(1, z[1], Zn, c1.x, c1.y) }
        { const float2 Zn = shx2(z[R - 2], 63); PAIRE(2, z[2], Zn, c2.x, c2.y) }
        { const float2 Zn = shx2(z[R - 3], 63); PAIRE(3, z[3], Zn, c3.x, c3.y) }
        #pragma unroll
        for (int g = 4; g <= R2_; g += 4) {
            c0 = cmulf(c0, ub4); c1 = cmulf(c1, ub4);
            c2 = cmulf(c2, ub4); c3 = cmulf(c3, ub4);
            { const float2 Zn = shx2(z[R - g], 63); PAIRE(g, z[g], Zn, c0.x, c0.y) }
            if (g + 1 <= R2_) { const float2 Zn = shx2(z[R - g - 1], 63); PAIRE(g + 1, z[g + 1], Zn, c1.x, c1.y) }
            if (g + 2 <= R2_) { const float2 Zn = shx2(z[R - g - 2], 63); PAIRE(g + 2, z[g + 2], Zn, c2.x, c2.y) }
            if (g + 3 <= R2_) { const float2 Zn = shx2(z[R - g - 3], 63); PAIRE(g + 3, z[g + 3], Zn, c3.x, c3.y) }
        }
    }
#undef PAIRE
#undef SWZK

    // coalesced transpose-out: raw (still-swizzled) rows -> global A rows
    if (valid) {
        const uint4* src = powsU + sub * (KPAD / 8);
        uint4* dst = (uint4*)(pows_g + (size_t)((size_t)b * n0 + t) * KPAD);
        #pragma unroll
        for (int w = 0; w < (NOCT + 63) / 64; ++w) {
            const int oct = p + 64 * w;
            if (oct < NOCT) dst[oct] = src[oct];
        }
    }
}

// ============ NEW PATH: mel convert (bakes the involution into melT) ============
template<int KPAD, int LOGR, int R, int K>
__global__ void melcvt_kernel(const float* __restrict__ mel,
                              unsigned short* __restrict__ melT) {
    const int idx = blockIdx.x * 256 + threadIdx.x;
    if (idx >= NMEL * KPAD) return;
    const int n = idx / KPAD, pos = idx - n * KPAD;
    const int k = (pos & ~(R - 1)) | ((pos & (R - 1)) ^ ((pos >> LOGR) & (R - 1)));
    unsigned short v = 0;
    if (k < K) {
        const unsigned u = __float_as_uint(mel[(size_t)k * NMEL + n]);
        v = (unsigned short)((u + 0x7FFF + ((u >> 16) & 1)) >> 16);   // RNE
    }
    melT[(size_t)n * KPAD + pos] = v;
}

// ============ NEW PATH: mel GEMM via MFMA + log + strided store ============
// D[frame][mel] = sum_pos A[frame][pos]*B[mel][pos]; A,B both row-major by
// output dim -> each fragment is one contiguous 16B load. 4 waves split K,
// LDS reduce, wave 0 epilogues.
template<int KPAD, int SZI>
__global__ __launch_bounds__(256)
void melgemm_kernel(const unsigned short* __restrict__ powsA,
                    const unsigned short* __restrict__ melT,
                    float* __restrict__ out, int Mvalid) {
    constexpr int NCH = KPAD / 32;
    __shared__ float red[3][16 * NMEL];

    const int tid = threadIdx.x;
    const int w   = tid >> 6;
    const int l   = tid & 63;
    const int mt  = blockIdx.x;

    const unsigned short* Ap = powsA + (size_t)(mt * 16 + (l & 15)) * KPAD + (l >> 4) * 8;
    const unsigned short* Bp = melT + (size_t)(l & 15) * KPAD + (l >> 4) * 8;

    f32x4 acc[5];
    const f32x4 z4 = {0.0f, 0.0f, 0.0f, 0.0f};
    #pragma unroll
    for (int nt = 0; nt < 5; ++nt) acc[nt] = z4;

    const int cpw = (NCH + 3) >> 2;
    const int c0 = w * cpw;
    const int c1 = (c0 + cpw < NCH) ? (c0 + cpw) : NCH;
    for (int c = c0; c < c1; ++c) {
        const bf16x8 a = *(const bf16x8*)(Ap + c * 32);
        #pragma unroll
        for (int nt = 0; nt < 5; ++nt) {
            const bf16x8 bb = *(const bf16x8*)(Bp + (size_t)nt * 16 * KPAD + c * 32);
            acc[nt] = __builtin_amdgcn_mfma_f32_16x16x32_bf16(a, bb, acc[nt], 0, 0, 0);
        }
    }

    if (w > 0) {
        #pragma unroll
        for (int nt = 0; nt < 5; ++nt) {
            #pragma unroll
            for (int q = 0; q < 4; ++q) {
                const int row = (l >> 4) * 4 + q;
                const int col = nt * 16 + (l & 15);
                red[w - 1][row * NMEL + col] = acc[nt][q];
            }
        }
    }
    __syncthreads();
    if (w == 0) {
        #pragma unroll
        for (int nt = 0; nt < 5; ++nt) {
            #pragma unroll
            for (int q = 0; q < 4; ++q) {
                const int row = (l >> 4) * 4 + q;
                const int col = nt * 16 + (l & 15);
                float v = acc[nt][q] + red[0][row * NMEL + col]
                        + red[1][row * NMEL + col] + red[2][row * NMEL + col];
                const int frame = mt * 16 + row;
                if (frame < Mvalid)
                    out[((size_t)frame * NMEL + col) * 3 + SZI] = logf(v + 1e-16f);
            }
        }
    }
}

// ================== FALLBACK (exact R7 kernel, known-passing) ==================
template<int FLEN, int SZI>
__global__ __launch_bounds__(512, 4)
void spect_kernel(const float* __restrict__ x, const float* __restrict__ win,
                  const float* __restrict__ mel, float* __restrict__ out,
                  int T, int n0) {
    constexpr int N    = FLEN / 2;
    constexpr int R    = N / 64;
    constexpr int LOGR = (R == 32) ? 5 : ((R == 16) ? 4 : 3);
    constexpr int R2_  = R / 2;
    constexpr int K    = N + 1;
    constexpr int KP   = N + 8;
    constexpr int HALF = FLEN / 2;
    constexpr int NT   = 512;
    constexpr int FPB  = 8;
    constexpr float PI = 3.14159265358979f;

    __shared__ uint4 pows4[KP];
    __shared__ float res[FPB * NMEL];
    unsigned short* pows = (unsigned short*)pows4;

    const int tid = threadIdx.x;
    const int sub = tid >> 6;
    const int p   = tid & 63;
    const int s   = brev6f(p);
    const int b   = blockIdx.y;
    const int t0  = blockIdx.x * FPB;

    for (int i = tid; i < FPB * NMEL; i += NT) res[i] = 0.0f;

    float2 W32s, W16s, W8s, W4s, W2s, wl, Pp, ub;
    float sg32, sg16, sg8, sg4, sg2, sg1;
    {
        float s_, c_;
        __sincosf(-PI * (float)(p & 31) / 32.0f, &s_, &c_);
        W32s = (p & 32) ? make_float2(c_, s_) : make_float2(1.0f, 0.0f);
        sg32 = (p & 32) ? -1.0f : 1.0f;
        __sincosf(-PI * (float)(p & 15) / 16.0f, &s_, &c_);
        W16s = (p & 16) ? make_float2(c_, s_) : make_float2(1.0f, 0.0f);
        sg16 = (p & 16) ? -1.0f : 1.0f;
        __sincosf(-PI * (float)(p & 7) / 8.0f, &s_, &c_);
        W8s  = (p & 8) ? make_float2(c_, s_) : make_float2(1.0f, 0.0f);
        sg8  = (p & 8) ? -1.0f : 1.0f;
        __sincosf(-PI * (float)(p & 3) / 4.0f, &s_, &c_);
        W4s  = (p & 4) ? make_float2(c_, s_) : make_float2(1.0f, 0.0f);
        sg4  = (p & 4) ? -1.0f : 1.0f;
        __sincosf(-PI * (float)(p & 1) / 2.0f, &s_, &c_);
        W2s  = (p & 2) ? make_float2(c_, s_) : make_float2(1.0f, 0.0f);
        sg2  = (p & 2) ? -1.0f : 1.0f;
        sg1  = (p & 1) ? -1.0f : 1.0f;
        __sincosf(-2.0f * PI * (float)p / (float)N, &s_, &c_); wl = make_float2(c_, s_);
        __sincosf(PI * (float)s / 64.0f, &s_, &c_);             Pp = make_float2(c_, s_);
        __sincosf(PI / (float)N, &s_, &c_);                     ub = make_float2(c_, s_);
    }
    const int mpart = brev6f((64 - s) & 63);

    const float* xb = x + (size_t)b * (size_t)T;
    const int Tp = T + HALF;

    const int t = t0 + sub;
    const bool valid = (t < n0);
    const int start = HOP * t;
    int pad = start + FLEN - Tp; if (pad < 0) pad = 0;
    const int base = start - pad - HALF;

    float2 z[R];
    if (pad == 0 && base >= 0 && valid) {
        const float*  xp = xb + base + 2 * p;
        const float2* wp = ((const float2*)win) + p;
        #pragma unroll
        for (int j = 0; j < R; ++j) {
            const int q = brevn(j, LOGR);
            const float2 wv = wp[64 * q];
            z[j] = make_float2(xp[128 * q] * wv.x, xp[128 * q + 1] * wv.y);
        }
    } else {
        #pragma unroll
        for (int j = 0; j < R; ++j) {
            const int q  = brevn(j, LOGR);
            const int i  = 64 * q + p;
            const int j0 = 2 * i;
            const float2 wv = ((const float2*)win)[i];
            const int xi0 = base + j0;
            float v0 = (valid && j0 >= pad     && xi0 >= 0)     ? xb[xi0] * wv.x     : 0.0f;
            float v1 = (valid && j0 + 1 >= pad && xi0 + 1 >= 0) ? xb[xi0 + 1] * wv.y : 0.0f;
            z[j] = make_float2(v0, v1);
        }
    }

    #pragma unroll
    for (int h = 1; h < R; h <<= 1) {
        #pragma unroll
        for (int base2 = 0; base2 < R; base2 += 2 * h) {
            #pragma unroll
            for (int i = 0; i < h; ++i) {
                const float2 W  = w32t((16 * i) / h);
                const float2 tt = cmulf(W, z[base2 + i + h]);
                const float2 aa = z[base2 + i];
                z[base2 + i]     = cadd(aa, tt);
                z[base2 + i + h] = csub(aa, tt);
            }
        }
    }

    {
        const float2 w2c = cmulf(wl, wl);
        const float2 w3c = cmulf(w2c, wl);
        const float2 w4c = cmulf(w2c, w2c);
        z[1] = cmulf(z[1], wl);
        z[2] = cmulf(z[2], w2c);
        z[3] = cmulf(z[3], w3c);
        float2 a0 = w4c, a1 = cmulf(wl, w4c), a2 = cmulf(w2c, w4c), a3 = cmulf(w3c, w4c);
        #pragma unroll
        for (int g = 4; g < R; g += 4) {
            z[g]     = cmulf(z[g],     a0);
            z[g + 1] = cmulf(z[g + 1], a1);
            z[g + 2] = cmulf(z[g + 2], a2);
            z[g + 3] = cmulf(z[g + 3], a3);
            if (g + 4 < R) {
                a0 = cmulf(a0, w4c); a1 = cmulf(a1, w4c);
                a2 = cmulf(a2, w4c); a3 = cmulf(a3, w4c);
            }
        }
    }

#define XSTAGE(MASK, W, SG) { \
        _Pragma("unroll") \
        for (int j = 0; j < R; ++j) { \
            const float2 xq = shx2(z[j], MASK); \
            const float2 d  = make_float2(fmaf(SG, z[j].x, xq.x), \
                                          fmaf(SG, z[j].y, xq.y)); \
            z[j] = cmulf(d, W); \
        } }
    XSTAGE(32, W32s, sg32)
    XSTAGE(16, W16s, sg16)
    XSTAGE(8,  W8s,  sg8)
    XSTAGE(4,  W4s,  sg4)
    XSTAGE(2,  W2s,  sg2)
    #pragma unroll
    for (int j = 0; j < R; ++j) {
        const float2 xq = shx2(z[j], 1);
        z[j] = make_float2(fmaf(sg1, z[j].x, xq.x), fmaf(sg1, z[j].y, xq.y));
    }
#undef XSTAGE

#define PAIRE(RR, ZK, ZN, CW, SW) { \
        const float Er = 0.5f * ((ZK).x + (ZN).x), Ei = 0.5f * ((ZK).y - (ZN).y); \
        const float Or = 0.5f * ((ZK).y + (ZN).y), Oi = -0.5f * ((ZK).x - (ZN).x); \
        const float Tr = (CW) * Or + (SW) * Oi; \
        const float Ti = (CW) * Oi - (SW) * Or; \
        const float Xr0 = Er + Tr, Xi0 = Ei + Ti; \
        const float Xr1 = Er - Tr, Xi1 = Ei - Ti; \
        const float pw0 = Xr0 * Xr0 + Xi0 * Xi0; \
        const float pw1 = Xr1 * Xr1 + Xi1 * Xi1; \
        const int k0b  = R * s + (RR); \
        const int km   = N - k0b; \
        const int row0 = (k0b & ~(R - 1)) | ((k0b & (R - 1)) ^ (s & 7)); \
        const int row1 = (km  & ~(R - 1)) | ((km  & (R - 1)) ^ ((km >> LOGR) & 7)); \
        pows[row0 * 8 + sub] = bf16t(pw0); \
        pows[row1 * 8 + sub] = bf16t(pw1); }

    {
        const float2 ub2 = cmulf(ub, ub);
        const float2 ub4 = cmulf(ub2, ub2);
        float2 c0 = Pp, c1 = cmulf(Pp, ub), c2 = cmulf(Pp, ub2), c3 = cmulf(c1, ub2);
        {
            const float2 Zn = shidx2(z[0], mpart);
            PAIRE(0, z[0], Zn, c0.x, c0.y)
        }
        { const float2 Zn = shx2(z[R - 1], 63); PAIRE(1, z[1], Zn, c1.x, c1.y) }
        { const float2 Zn = shx2(z[R - 2], 63); PAIRE(2, z[2], Zn, c2.x, c2.y) }
        { const float2 Zn = shx2(z[R - 3], 63); PAIRE(3, z[3], Zn, c3.x, c3.y) }
        #pragma unroll
        for (int g = 4; g <= R2_; g += 4) {
            c0 = cmulf(c0, ub4); c1 = cmulf(c1, ub4);
            c2 = cmulf(c2, ub4); c3 = cmulf(c3, ub4);
            { const float2 Zn = shx2(z[R - g], 63); PAIRE(g, z[g], Zn, c0.x, c0.y) }
            if (g + 1 <= R2_) { const float2 Zn = shx2(z[R - g - 1], 63); PAIRE(g + 1, z[g + 1], Zn, c1.x, c1.y) }
            if (g + 2 <= R2_) { const float2 Zn = shx2(z[R - g - 2], 63); PAIRE(g + 2, z[g + 2], Zn, c2.x, c2.y) }
            if (g + 3 <= R2_) { const float2 Zn = shx2(z[R - g - 3], 63); PAIRE(g + 3, z[g + 3], Zn, c3.x, c3.y) }
        }
    }
#undef PAIRE

    __syncthreads();

    constexpr int NCH = 25;
    constexpr int CH  = (K + NCH - 1) / NCH;
    if (tid < NCH * 20) {
        const int g  = tid % 20;
        const int cc = tid / 20;
        const int k0 = cc * CH;
        const int k1 = (k0 + CH < K) ? (k0 + CH) : K;
        float acc[FPB][4];
        #pragma unroll
        for (int f2 = 0; f2 < FPB; ++f2) {
            acc[f2][0] = 0.f; acc[f2][1] = 0.f; acc[f2][2] = 0.f; acc[f2][3] = 0.f;
        }
        #pragma unroll 4
        for (int k = k0; k < k1; ++k) {
            const int kmel = (k & ~(R - 1)) | ((k & (R - 1)) ^ ((k >> LOGR) & 7));
            const float4 mr = *(const float4*)(mel + (size_t)kmel * NMEL + 4 * g);
            const uint4 pv = pows4[k];
#define ACC2(W32, BASE) { \
            const float p0 = __uint_as_float((W32) << 16); \
            const float p1 = __uint_as_float((W32) & 0xFFFF0000u); \
            acc[BASE][0] += p0 * mr.x; acc[BASE][1] += p0 * mr.y; \
            acc[BASE][2] += p0 * mr.z; acc[BASE][3] += p0 * mr.w; \
            acc[(BASE)+1][0] += p1 * mr.x; acc[(BASE)+1][1] += p1 * mr.y; \
            acc[(BASE)+1][2] += p1 * mr.z; acc[(BASE)+1][3] += p1 * mr.w; }
            ACC2(pv.x, 0) ACC2(pv.y, 2) ACC2(pv.z, 4) ACC2(pv.w, 6)
#undef ACC2
        }
        #pragma unroll
        for (int f2 = 0; f2 < FPB; ++f2) {
            #pragma unroll
            for (int mi = 0; mi < 4; ++mi) {
                atomicAdd(&res[f2 * NMEL + 4 * g + mi], acc[f2][mi]);
            }
        }
    }
    __syncthreads();

    const size_t outbase = (size_t)b * (size_t)n0 * NMEL * 3;
    for (int i = tid; i < FPB * NMEL; i += NT) {
        const int f2 = i / NMEL;
        const int m  = i % NMEL;
        const int tt = t0 + f2;
        if (tt < n0) {
            out[outbase + ((size_t)tt * NMEL + m) * 3 + SZI] = logf(res[i] + 1e-16f);
        }
    }
}

extern "C" void kernel_launch(void* const* d_in, const int* in_sizes, int n_in,
                              void* d_out, int out_size, void* d_ws, size_t ws_size,
                              hipStream_t stream) {
    const float* x  = (const float*)d_in[0];
    const float* w1 = (const float*)d_in[1];
    const float* m1 = (const float*)d_in[2];
    const float* w2 = (const float*)d_in[3];
    const float* m2 = (const float*)d_in[4];
    const float* w4 = (const float*)d_in[5];
    const float* m4 = (const float*)d_in[6];
    float* out = (float*)d_out;

    const int B  = 8;
    const int T  = in_sizes[0] / B;
    const int n0 = (T + 512 + 440) / 441;   // ceil((T + 1024/2) / 441)

    const size_t M    = (size_t)B * (size_t)n0;
    const size_t Mpad = (M + 15) & ~(size_t)15;
    const size_t KP1 = 544, KP2 = 1056, KP4 = 2080;
    const size_t need = (Mpad + NMEL) * (KP1 + KP2 + KP4) * 2;

    if (ws_size >= need) {
        unsigned short* p1  = (unsigned short*)d_ws;
        unsigned short* p2  = p1 + Mpad * KP1;
        unsigned short* p4  = p2 + Mpad * KP2;
        unsigned short* m1t = p4 + Mpad * KP4;
        unsigned short* m2t = m1t + NMEL * KP1;
        unsigned short* m4t = m2t + NMEL * KP2;

        melcvt_kernel< 544, 3,  8,  513><<<(NMEL *  544 + 255) / 256, 256, 0, stream>>>(m1, m1t);
        melcvt_kernel<1056, 4, 16, 1025><<<(NMEL * 1056 + 255) / 256, 256, 0, stream>>>(m2, m2t);
        melcvt_kernel<2080, 5, 32, 2049><<<(NMEL * 2080 + 255) / 256, 256, 0, stream>>>(m4, m4t);

        const int gx = (n0 + 3) / 4;
        fft_kernel<1024,  544><<<dim3(gx, B), 256, 0, stream>>>(x, w1, p1, T, n0);
        fft_kernel<2048, 1056><<<dim3(gx, B), 256, 0, stream>>>(x, w2, p2, T, n0);
        fft_kernel<4096, 2080><<<dim3(gx, B), 256, 0, stream>>>(x, w4, p4, T, n0);

        const int mt = (int)(Mpad / 16);
        melgemm_kernel< 544, 0><<<mt, 256, 0, stream>>>(p1, m1t, out, (int)M);
        melgemm_kernel<1056, 1><<<mt, 256, 0, stream>>>(p2, m2t, out, (int)M);
        melgemm_kernel<2080, 2><<<mt, 256, 0, stream>>>(p4, m4t, out, (int)M);
    } else {
        const int gx = (n0 + 7) / 8;
        spect_kernel<1024, 0><<<dim3(gx, B), 512, 0, stream>>>(x, w1, m1, out, T, n0);
        spect_kernel<2048, 1><<<dim3(gx, B), 512, 0, stream>>>(x, w2, m2, out, T, n0);
        spect_kernel<4096, 2><<<dim3(gx, B), 512, 0, stream>>>(x, w4, m4, out, T, n0);
    }
}